// Round 5
// baseline (233.334 us; speedup 1.0000x reference)
//
#include <hip/hip_runtime.h>
#include <hip/hip_bf16.h>

#define N_NODES 100000
#define N_EDGES 1250000
#define N_FEAT 128
#define NHID 64
#define NUM_GRAPHS 256
#define NB_SCAN 98   // 98*1024 >= 100000

typedef __attribute__((ext_vector_type(8))) short short8;
typedef __attribute__((ext_vector_type(16))) float float16;
typedef __attribute__((ext_vector_type(4))) int int4v;

static __device__ __forceinline__ short f2bf(float x) {
    __hip_bfloat16 b = __float2bfloat16(x);
    return *reinterpret_cast<short*>(&b);
}
static __device__ __forceinline__ float bf2f(short s) {
    __hip_bfloat16 b = *reinterpret_cast<__hip_bfloat16*>(&s);
    return __bfloat162float(b);
}
// pack two floats as bf16 pair (a -> low16, b -> high16)
static __device__ __forceinline__ int pk2(float a, float b) {
    unsigned lo = (unsigned short)f2bf(a);
    unsigned hi = (unsigned short)f2bf(b);
    return (int)(lo | (hi << 16));
}

// ---------------------------------------------------------------------------
// K0: cnt = 0, pooled = 0
// ---------------------------------------------------------------------------
__global__ void k0_init(int* __restrict__ cnt, float* __restrict__ pooled) {
    int i = blockIdx.x * blockDim.x + threadIdx.x;
    if (i < N_NODES) cnt[i] = 0;
    if (i < NUM_GRAPHS * NHID) pooled[i] = 0.0f;
}

// ---------------------------------------------------------------------------
// K1: edge MLP, all-MFMA (one wave per 32 edges, grid-stride).
// R5: ea software-pipelined across iterations; half-wave exchange done as
// packed bf16 (8 shfl_xor instead of 16 + fused relu/cvt).
// Fused epilogue: edge_w store + int histogram cnt[col]++ for live edges.
// ---------------------------------------------------------------------------
__global__ __launch_bounds__(256) void k1_edge_mlp(
    const float* __restrict__ ea, const float* __restrict__ W1,
    const float* __restrict__ b1, const float* __restrict__ W2,
    const float* __restrict__ b2, const float* __restrict__ W3,
    const float* __restrict__ b3, const int* __restrict__ eidx,
    float* __restrict__ edge_w, int* __restrict__ cnt)
{
    const int lane = threadIdx.x & 63;
    const int l31 = lane & 31;
    const int h = lane >> 5;
    const int wslot = blockIdx.x * 4 + (threadIdx.x >> 6);
    const int S = gridDim.x * 4;
    const float b3v = b3[0];

    // layer1 A-frags: W1^T hi/lo. A[m=t*32+l31][k=8h+j] = W1[k][m], k<5.
    short8 a1hi[2], a1lo[2];
    #pragma unroll
    for (int t = 0; t < 2; ++t)
        #pragma unroll
        for (int j = 0; j < 8; ++j) {
            int k = 8 * h + j;
            float v = (k < 5) ? W1[k * NHID + t * 32 + l31] : 0.0f;
            short hi = f2bf(v);
            a1hi[t][j] = hi;
            a1lo[t][j] = f2bf(v - bf2f(hi));
        }

    float b1r[2][16];
    #pragma unroll
    for (int t = 0; t < 2; ++t)
        #pragma unroll
        for (int r = 0; r < 16; ++r)
            b1r[t][r] = b1[t * 32 + (r & 3) + 8 * (r >> 2) + 4 * h];

    short8 afrag[2][4];
    #pragma unroll
    for (int t = 0; t < 2; ++t)
        #pragma unroll
        for (int kk = 0; kk < 4; ++kk)
            #pragma unroll
            for (int j = 0; j < 8; ++j) {
                int k = kk * 16 + h * 8 + j;
                afrag[t][kk][j] = f2bf(W2[k * NHID + t * 32 + l31]);
            }

    float b2r[2][16], w3r[2][16];
    #pragma unroll
    for (int t = 0; t < 2; ++t)
        #pragma unroll
        for (int r = 0; r < 16; ++r) {
            int hid = t * 32 + (r & 3) + 8 * (r >> 2) + 4 * h;
            b2r[t][r] = b2[hid];
            w3r[t][r] = W3[hid];
        }

    const int NCHUNK = (N_EDGES + 31) / 32;

    // ---- prologue: load first chunk's ea (h==0 lanes only)
    float pe[5] = {0.f, 0.f, 0.f, 0.f, 0.f};
    if (wslot < NCHUNK && h == 0) {
        int e = wslot * 32 + l31;
        int ec = (e < N_EDGES) ? e : (N_EDGES - 1);
        #pragma unroll
        for (int j = 0; j < 5; ++j) pe[j] = ea[ec * 5 + j];
    }

    for (int chunk = wslot; chunk < NCHUNK; chunk += S) {
        // ---- prefetch next iteration's ea (independent -> scheduled early)
        int nchunk = chunk + S;
        float ne[5] = {0.f, 0.f, 0.f, 0.f, 0.f};
        if (nchunk < NCHUNK && h == 0) {
            int e2 = nchunk * 32 + l31;
            int ec2 = (e2 < N_EDGES) ? e2 : (N_EDGES - 1);
            #pragma unroll
            for (int j = 0; j < 5; ++j) ne[j] = ea[ec2 * 5 + j];
        }

        int e = chunk * 32 + l31;
        bool valid = e < N_EDGES;

        // ---- ea B-frags hi/lo: B[k=8h+j][n=l31]; nonzero only h==0, j<5
        short8 behi, belo;
        #pragma unroll
        for (int j = 0; j < 8; ++j) {
            float v = (h == 0 && j < 5) ? pe[j] : 0.0f;
            short hi = f2bf(v);
            behi[j] = hi;
            belo[j] = f2bf(v - bf2f(hi));
        }

        // ---- layer1 MFMAs (C init = b1)
        float16 acc1a, acc1b;
        #pragma unroll
        for (int r = 0; r < 16; ++r) { acc1a[r] = b1r[0][r]; acc1b[r] = b1r[1][r]; }
        acc1a = __builtin_amdgcn_mfma_f32_32x32x16_bf16(a1hi[0], behi, acc1a, 0, 0, 0);
        acc1a = __builtin_amdgcn_mfma_f32_32x32x16_bf16(a1hi[0], belo, acc1a, 0, 0, 0);
        acc1a = __builtin_amdgcn_mfma_f32_32x32x16_bf16(a1lo[0], behi, acc1a, 0, 0, 0);
        acc1b = __builtin_amdgcn_mfma_f32_32x32x16_bf16(a1hi[1], behi, acc1b, 0, 0, 0);
        acc1b = __builtin_amdgcn_mfma_f32_32x32x16_bf16(a1hi[1], belo, acc1b, 0, 0, 0);
        acc1b = __builtin_amdgcn_mfma_f32_32x32x16_bf16(a1lo[1], behi, acc1b, 0, 0, 0);

        // ---- packed-bf16 half-wave exchange -> layer2 B-frags
        // lane needs h1[k=kk*16+8h+j][edge l31]; relu fused into extract.
        short8 bf2v[4];
        #pragma unroll
        for (int kk = 0; kk < 4; ++kk) {
            float lv0, lv1, lv2, lv3, hv0, hv1, hv2, hv3;
            if (kk >> 1) {
                int o = 8 * (kk & 1);
                lv0 = fmaxf(acc1b[o + 0], 0.f); lv1 = fmaxf(acc1b[o + 1], 0.f);
                lv2 = fmaxf(acc1b[o + 2], 0.f); lv3 = fmaxf(acc1b[o + 3], 0.f);
                hv0 = fmaxf(acc1b[o + 4], 0.f); hv1 = fmaxf(acc1b[o + 5], 0.f);
                hv2 = fmaxf(acc1b[o + 6], 0.f); hv3 = fmaxf(acc1b[o + 7], 0.f);
            } else {
                int o = 8 * (kk & 1);
                lv0 = fmaxf(acc1a[o + 0], 0.f); lv1 = fmaxf(acc1a[o + 1], 0.f);
                lv2 = fmaxf(acc1a[o + 2], 0.f); lv3 = fmaxf(acc1a[o + 3], 0.f);
                hv0 = fmaxf(acc1a[o + 4], 0.f); hv1 = fmaxf(acc1a[o + 5], 0.f);
                hv2 = fmaxf(acc1a[o + 6], 0.f); hv3 = fmaxf(acc1a[o + 7], 0.f);
            }
            int p_lv0 = pk2(lv0, lv1), p_lv1 = pk2(lv2, lv3);
            int p_hv0 = pk2(hv0, hv1), p_hv1 = pk2(hv2, hv3);
            int send0 = h ? p_lv0 : p_hv0;
            int send1 = h ? p_lv1 : p_hv1;
            int r0 = __shfl_xor(send0, 32, 64);
            int r1 = __shfl_xor(send1, 32, 64);
            int4v fi;
            fi.x = h ? r0 : p_lv0;      // j0,j1
            fi.y = h ? r1 : p_lv1;      // j2,j3
            fi.z = h ? p_hv0 : r0;      // j4,j5
            fi.w = h ? p_hv1 : r1;      // j6,j7
            bf2v[kk] = __builtin_bit_cast(short8, fi);
        }

        // ---- layer2 MFMAs (C init = b2)
        float16 c0, c1;
        #pragma unroll
        for (int r = 0; r < 16; ++r) { c0[r] = b2r[0][r]; c1[r] = b2r[1][r]; }
        #pragma unroll
        for (int kk = 0; kk < 4; ++kk) {
            c0 = __builtin_amdgcn_mfma_f32_32x32x16_bf16(afrag[0][kk], bf2v[kk], c0, 0, 0, 0);
            c1 = __builtin_amdgcn_mfma_f32_32x32x16_bf16(afrag[1][kk], bf2v[kk], c1, 0, 0, 0);
        }

        // ---- layer3
        float partial = 0.0f;
        #pragma unroll
        for (int r = 0; r < 16; ++r) {
            partial += fmaxf(c0[r], 0.0f) * w3r[0][r];
            partial += fmaxf(c1[r], 0.0f) * w3r[1][r];
        }
        float total = partial + __shfl_xor(partial, 32, 64);
        float w = fmaxf(total + b3v, 0.0f);

        if (h == 0 && valid) {
            edge_w[e] = w;
            if (w > 0.0f) atomicAdd(&cnt[eidx[N_EDGES + e]], 1);
        }

        #pragma unroll
        for (int j = 0; j < 5; ++j) pe[j] = ne[j];
    }
}

// ---------------------------------------------------------------------------
// Scan: cnt[100000] -> exclusive offsets off[100001]; cur = off copy.
// ---------------------------------------------------------------------------
__global__ __launch_bounds__(1024) void s1_blocksum(const int* __restrict__ cnt,
                                                    int* __restrict__ bsum) {
    __shared__ int sd[1024];
    int t = threadIdx.x;
    int i = blockIdx.x * 1024 + t;
    sd[t] = (i < N_NODES) ? cnt[i] : 0;
    __syncthreads();
    #pragma unroll
    for (int d = 512; d > 0; d >>= 1) {
        if (t < d) sd[t] += sd[t + d];
        __syncthreads();
    }
    if (t == 0) bsum[blockIdx.x] = sd[0];
}

__global__ __launch_bounds__(128) void s2_scanbase(const int* __restrict__ bsum,
                                                   int* __restrict__ bbase,
                                                   int* __restrict__ off) {
    __shared__ int sd[128];
    int t = threadIdx.x;
    int v = (t < NB_SCAN) ? bsum[t] : 0;
    sd[t] = v;
    __syncthreads();
    #pragma unroll
    for (int d = 1; d < 128; d <<= 1) {
        int u = (t >= d) ? sd[t - d] : 0;
        __syncthreads();
        sd[t] += u;
        __syncthreads();
    }
    if (t < NB_SCAN) bbase[t] = sd[t] - v;
    if (t == 127) off[N_NODES] = sd[127];
}

__global__ __launch_bounds__(1024) void s3_blockscan(const int* __restrict__ cnt,
                                                     const int* __restrict__ bbase,
                                                     int* __restrict__ off,
                                                     int* __restrict__ cur) {
    __shared__ int sd[1024];
    int t = threadIdx.x;
    int i = blockIdx.x * 1024 + t;
    int c = (i < N_NODES) ? cnt[i] : 0;
    sd[t] = c;
    __syncthreads();
    #pragma unroll
    for (int d = 1; d < 1024; d <<= 1) {
        int v = (t >= d) ? sd[t - d] : 0;
        __syncthreads();
        sd[t] += v;
        __syncthreads();
    }
    if (i < N_NODES) {
        int ex = sd[t] - c + bbase[blockIdx.x];
        off[i] = ex;
        cur[i] = ex;
    }
}

// ---------------------------------------------------------------------------
// K_place: scatter live edges into CSR slots (packed {row, w} int2).
// ---------------------------------------------------------------------------
__global__ void k_place(const float* __restrict__ edge_w, const int* __restrict__ eidx,
                        int* __restrict__ cur, int2* __restrict__ recs) {
    int e = blockIdx.x * 256 + threadIdx.x;
    if (e >= N_EDGES) return;
    float w = edge_w[e];
    if (w <= 0.0f) return;
    int col = eidx[N_EDGES + e];
    int pos = atomicAdd(&cur[col], 1);
    recs[pos] = make_int2(eidx[e], __float_as_int(w));
}

// ---------------------------------------------------------------------------
// K_deg: dinv[n] = rsqrt(1 + sum of w over n's in-segment). Contiguous reads.
// ---------------------------------------------------------------------------
__global__ void k_deg(const int* __restrict__ off, const int2* __restrict__ recs,
                      float* __restrict__ dinv) {
    int n = blockIdx.x * 256 + threadIdx.x;
    if (n >= N_NODES) return;
    int o0 = off[n], o1 = off[n + 1];
    float s = 1.0f;
    for (int j = o0; j < o1; ++j) s += __int_as_float(recs[j].y);
    dinv[n] = rsqrtf(s);
}

// ---------------------------------------------------------------------------
// K3: xws[n] = dinv[n]*(x[n]@Wg) via MFMA; one wave per 32 nodes.
// ---------------------------------------------------------------------------
__global__ __launch_bounds__(256) void k3_xw(
    const float* __restrict__ x, const float* __restrict__ Wg,
    const float* __restrict__ dinv, float* __restrict__ xws)
{
    const int lane = threadIdx.x & 63;
    const int l31 = lane & 31;
    const int h = lane >> 5;
    const int wslot = blockIdx.x * 4 + (threadIdx.x >> 6);

    short8 bw[8][2];
    #pragma unroll
    for (int kk = 0; kk < 8; ++kk)
        #pragma unroll
        for (int u = 0; u < 2; ++u)
            #pragma unroll
            for (int j = 0; j < 8; ++j)
                bw[kk][u][j] = f2bf(Wg[(kk * 16 + 8 * h + j) * NHID + u * 32 + l31]);

    const int NC = N_NODES / 32;
    for (int chunk = wslot; chunk < NC; chunk += gridDim.x * 4) {
        int base = chunk * 32;
        const float* xrow = x + (size_t)(base + l31) * N_FEAT + 8 * h;

        float16 acc0, acc1;
        #pragma unroll
        for (int r = 0; r < 16; ++r) { acc0[r] = 0.0f; acc1[r] = 0.0f; }

        #pragma unroll
        for (int kk = 0; kk < 8; ++kk) {
            float4 p = *(const float4*)(xrow + kk * 16);
            float4 q = *(const float4*)(xrow + kk * 16 + 4);
            short8 af;
            af[0] = f2bf(p.x); af[1] = f2bf(p.y); af[2] = f2bf(p.z); af[3] = f2bf(p.w);
            af[4] = f2bf(q.x); af[5] = f2bf(q.y); af[6] = f2bf(q.z); af[7] = f2bf(q.w);
            acc0 = __builtin_amdgcn_mfma_f32_32x32x16_bf16(af, bw[kk][0], acc0, 0, 0, 0);
            acc1 = __builtin_amdgcn_mfma_f32_32x32x16_bf16(af, bw[kk][1], acc1, 0, 0, 0);
        }

        #pragma unroll
        for (int r = 0; r < 16; ++r) {
            int node = base + (r & 3) + 8 * (r >> 2) + 4 * h;
            float dv = dinv[node];
            xws[node * NHID + l31] = acc0[r] * dv;
            xws[node * NHID + 32 + l31] = acc1[r] * dv;
        }
    }
}

// ---------------------------------------------------------------------------
// K4: fused gather + relu + pool. One wave per 8 consecutive nodes.
// ---------------------------------------------------------------------------
__global__ __launch_bounds__(256) void k4_gather_pool(
    const int* __restrict__ off, const int2* __restrict__ recs,
    const float* __restrict__ xws, const float* __restrict__ dinv,
    const float* __restrict__ bg, const int* __restrict__ batch,
    float* __restrict__ pooled)
{
    const int lane = threadIdx.x & 63;
    const int wv = blockIdx.x * 4 + (threadIdx.x >> 6);
    int n0 = wv * 8;
    if (n0 >= N_NODES) return;
    float bgl = bg[lane];
    float pacc = 0.0f;
    int curg = batch[n0];
    #pragma unroll
    for (int nn = 0; nn < 8; ++nn) {
        int n = n0 + nn;
        int g = batch[n];
        if (g != curg) {
            atomicAdd(&pooled[curg * NHID + lane], pacc);
            pacc = 0.0f;
            curg = g;
        }
        int o0 = off[n], o1 = off[n + 1];
        float acc = xws[(size_t)n * NHID + lane];
        if (o0 < o1) {
            int2 r = recs[o0];
            float gth = xws[(size_t)r.x * NHID + lane];
            for (int j = o0; j < o1 - 1; ++j) {
                int2 rn = recs[j + 1];
                float gn = xws[(size_t)rn.x * NHID + lane];
                acc = fmaf(__int_as_float(r.y), gth, acc);
                r = rn; gth = gn;
            }
            acc = fmaf(__int_as_float(r.y), gth, acc);
        }
        pacc += fmaxf(dinv[n] * acc + bgl, 0.0f);
    }
    atomicAdd(&pooled[curg * NHID + lane], pacc);
}

// ---------------------------------------------------------------------------
// K6: z = relu(pooled @ W_b1 + b_b1); out = z @ W_b2 + b_b2.
// ---------------------------------------------------------------------------
__global__ __launch_bounds__(64) void k6_final(
    const float* __restrict__ pooled, const float* __restrict__ Wb1,
    const float* __restrict__ bb1, const float* __restrict__ Wb2,
    const float* __restrict__ bb2, float* __restrict__ out) {
    __shared__ float p[NHID];
    int lane = threadIdx.x;
    int g = blockIdx.x;
    p[lane] = pooled[g * NHID + lane];
    __syncthreads();
    float z = bb1[lane];
    #pragma unroll
    for (int k = 0; k < NHID; ++k) z += p[k] * Wb1[k * NHID + lane];
    z = fmaxf(z, 0.0f) * Wb2[lane];
    #pragma unroll
    for (int off = 32; off > 0; off >>= 1)
        z += __shfl_down(z, off, 64);
    if (lane == 0) out[g] = z + bb2[0];
}

// ---------------------------------------------------------------------------
extern "C" void kernel_launch(void* const* d_in, const int* in_sizes, int n_in,
                              void* d_out, int out_size, void* d_ws, size_t ws_size,
                              hipStream_t stream) {
    const float* x        = (const float*)d_in[0];
    const float* ea       = (const float*)d_in[1];
    const float* W_e1     = (const float*)d_in[2];
    const float* b_e1     = (const float*)d_in[3];
    const float* W_e2     = (const float*)d_in[4];
    const float* b_e2     = (const float*)d_in[5];
    const float* W_e3     = (const float*)d_in[6];
    const float* b_e3     = (const float*)d_in[7];
    const float* W_g      = (const float*)d_in[8];
    const float* b_g      = (const float*)d_in[9];
    const float* W_b1     = (const float*)d_in[10];
    const float* b_b1     = (const float*)d_in[11];
    const float* W_b2     = (const float*)d_in[12];
    const float* b_b2     = (const float*)d_in[13];
    const int*   eidx     = (const int*)d_in[14];
    const int*   batch    = (const int*)d_in[15];
    float* out = (float*)d_out;

    char* wsb = (char*)d_ws;
    float* edge_w = (float*)wsb;                        // 1,250,000 f
    int*   cnt    = (int*)(wsb + 4 * 1250048);          // 100,000 i
    int*   off    = (int*)(wsb + 4 * 1350080);          // 100,001 i
    int*   cur    = (int*)(wsb + 4 * 1450112);          // 100,000 i
    int*   bsum   = (int*)(wsb + 4 * 1550144);          // 98 i
    int*   bbase  = (int*)(wsb + 4 * 1550272);          // 98 i
    float* dinv   = (float*)(wsb + 4 * 1550400);        // 100,000 f
    float* pooled = (float*)(wsb + 4 * 1650432);        // 16,384 f
    int2*  recs   = (int2*)(wsb + 4 * 1666880);         // up to 1,250,000 int2
    float* xws    = (float*)(wsb + 4 * 4166880);        // 6,400,000 f

    k0_init<<<dim3(391), dim3(256), 0, stream>>>(cnt, pooled);
    k1_edge_mlp<<<dim3(2048), dim3(256), 0, stream>>>(
        ea, W_e1, b_e1, W_e2, b_e2, W_e3, b_e3, eidx, edge_w, cnt);
    s1_blocksum<<<dim3(NB_SCAN), dim3(1024), 0, stream>>>(cnt, bsum);
    s2_scanbase<<<dim3(1), dim3(128), 0, stream>>>(bsum, bbase, off);
    s3_blockscan<<<dim3(NB_SCAN), dim3(1024), 0, stream>>>(cnt, bbase, off, cur);
    k_place<<<dim3((N_EDGES + 255) / 256), dim3(256), 0, stream>>>(edge_w, eidx, cur, recs);
    k_deg<<<dim3((N_NODES + 255) / 256), dim3(256), 0, stream>>>(off, recs, dinv);
    k3_xw<<<dim3(512), dim3(256), 0, stream>>>(x, W_g, dinv, xws);
    k4_gather_pool<<<dim3(3125), dim3(256), 0, stream>>>(off, recs, xws, dinv, b_g, batch, pooled);
    k6_final<<<dim3(NUM_GRAPHS), dim3(64), 0, stream>>>(pooled, W_b1, b_b1, W_b2, b_b2, out);
}

// Round 6
// 223.503 us; speedup vs baseline: 1.0440x; 1.0440x over previous
//
#include <hip/hip_runtime.h>
#include <hip/hip_bf16.h>

#define N_NODES 100000
#define N_EDGES 1250000
#define N_FEAT 128
#define NHID 64
#define NUM_GRAPHS 256
#define NB_SCAN 98   // 98*1024 >= 100000

typedef __attribute__((ext_vector_type(8))) short short8;
typedef __attribute__((ext_vector_type(16))) float float16;
typedef __attribute__((ext_vector_type(4))) int int4v;

static __device__ __forceinline__ short f2bf(float x) {
    __hip_bfloat16 b = __float2bfloat16(x);
    return *reinterpret_cast<short*>(&b);
}
static __device__ __forceinline__ float bf2f(short s) {
    __hip_bfloat16 b = *reinterpret_cast<__hip_bfloat16*>(&s);
    return __bfloat162float(b);
}
static __device__ __forceinline__ int pk2(float a, float b) {
    unsigned lo = (unsigned short)f2bf(a);
    unsigned hi = (unsigned short)f2bf(b);
    return (int)(lo | (hi << 16));
}

// ---------------------------------------------------------------------------
// K1: edge MLP, all-MFMA, 2 chunks (64 edges) per iteration for ILP.
// Biases folded into MFMAs: b1 as K=5 column of layer1 A (B has 1.0 there),
// b2 as a 5th K-group in layer2. Fused epilogue: edge_w store + cnt[col]++
// (int) + degf[col]+=w (float) for live edges.
// ---------------------------------------------------------------------------
__global__ __launch_bounds__(256) void k1_edge_mlp(
    const float* __restrict__ ea, const float* __restrict__ W1,
    const float* __restrict__ b1, const float* __restrict__ W2,
    const float* __restrict__ b2, const float* __restrict__ W3,
    const float* __restrict__ b3, const int* __restrict__ eidx,
    float* __restrict__ edge_w, int* __restrict__ cnt, float* __restrict__ degf)
{
    const int lane = threadIdx.x & 63;
    const int l31 = lane & 31;
    const int h = lane >> 5;
    const int wslot = blockIdx.x * 4 + (threadIdx.x >> 6);
    const int S = gridDim.x * 4;
    const float b3v = b3[0];

    // layer1 A-frags hi/lo with bias column: A[m=t*32+l31][k=8h+j] =
    //   W1[k][m] (k<5), b1[m] (k==5), 0 (k>5)
    short8 a1hi[2], a1lo[2];
    #pragma unroll
    for (int t = 0; t < 2; ++t)
        #pragma unroll
        for (int j = 0; j < 8; ++j) {
            int k = 8 * h + j;
            int m = t * 32 + l31;
            float v = (k < 5) ? W1[k * NHID + m] : ((k == 5) ? b1[m] : 0.0f);
            short hi = f2bf(v);
            a1hi[t][j] = hi;
            a1lo[t][j] = f2bf(v - bf2f(hi));
        }

    // layer2 A-frags: A[m=t*32+l31][k=kk*16+8h+j] = W2[k][m]
    short8 afrag[2][4];
    #pragma unroll
    for (int t = 0; t < 2; ++t)
        #pragma unroll
        for (int kk = 0; kk < 4; ++kk)
            #pragma unroll
            for (int j = 0; j < 8; ++j) {
                int k = kk * 16 + h * 8 + j;
                afrag[t][kk][j] = f2bf(W2[k * NHID + t * 32 + l31]);
            }

    // layer2 bias K-group: A[m][k=64] = b2[m]; B has 1.0 at k=64
    short8 a2b[2], bone;
    #pragma unroll
    for (int t = 0; t < 2; ++t)
        #pragma unroll
        for (int j = 0; j < 8; ++j)
            a2b[t][j] = (h == 0 && j == 0) ? f2bf(b2[t * 32 + l31]) : (short)0;
    #pragma unroll
    for (int j = 0; j < 8; ++j)
        bone[j] = (h == 0 && j == 0) ? f2bf(1.0f) : (short)0;

    // W3 at layer2 C-layout rows
    float w3r[2][16];
    #pragma unroll
    for (int t = 0; t < 2; ++t)
        #pragma unroll
        for (int r = 0; r < 16; ++r)
            w3r[t][r] = W3[t * 32 + (r & 3) + 8 * (r >> 2) + 4 * h];

    const int NCHUNK = (N_EDGES + 31) / 32;   // 39063
    const int PAIRS = (NCHUNK + 1) / 2;       // 19532

    for (int p = wslot; p < PAIRS; p += S) {
        int ch[2] = {2 * p, 2 * p + 1};

        // ---- ea B-frags hi/lo per chunk (bias 1.0 at j==5, h==0)
        short8 behi[2], belo[2];
        bool cvq[2];
        #pragma unroll
        for (int q = 0; q < 2; ++q) {
            int e = ch[q] * 32 + l31;
            cvq[q] = (ch[q] < NCHUNK) && (e < N_EDGES);
            int ec = (e < N_EDGES) ? e : (N_EDGES - 1);
            #pragma unroll
            for (int j = 0; j < 8; ++j) {
                float v = 0.0f;
                if (h == 0) {
                    if (j < 5) v = ea[ec * 5 + j];
                    else if (j == 5) v = 1.0f;
                }
                short hi = f2bf(v);
                behi[q][j] = hi;
                belo[q][j] = (h == 0 && j < 5) ? f2bf(v - bf2f(hi)) : (short)0;
            }
        }

        // ---- layer1 MFMAs (C init = 0; bias folded): 4 independent chains
        float16 A1[2][2];
        #pragma unroll
        for (int q = 0; q < 2; ++q)
            #pragma unroll
            for (int t = 0; t < 2; ++t)
                #pragma unroll
                for (int r = 0; r < 16; ++r) A1[q][t][r] = 0.0f;
        #pragma unroll
        for (int t = 0; t < 2; ++t)
            #pragma unroll
            for (int q = 0; q < 2; ++q) {
                A1[q][t] = __builtin_amdgcn_mfma_f32_32x32x16_bf16(a1hi[t], behi[q], A1[q][t], 0, 0, 0);
                A1[q][t] = __builtin_amdgcn_mfma_f32_32x32x16_bf16(a1hi[t], belo[q], A1[q][t], 0, 0, 0);
                A1[q][t] = __builtin_amdgcn_mfma_f32_32x32x16_bf16(a1lo[t], behi[q], A1[q][t], 0, 0, 0);
            }

        // ---- packed-bf16 half-wave exchange -> layer2 B-frags (relu fused)
        short8 bf2v[2][4];
        #pragma unroll
        for (int q = 0; q < 2; ++q) {
            #pragma unroll
            for (int kk = 0; kk < 4; ++kk) {
                float lv0, lv1, lv2, lv3, hv0, hv1, hv2, hv3;
                int o = 8 * (kk & 1);
                if (kk >> 1) {
                    lv0 = fmaxf(A1[q][1][o + 0], 0.f); lv1 = fmaxf(A1[q][1][o + 1], 0.f);
                    lv2 = fmaxf(A1[q][1][o + 2], 0.f); lv3 = fmaxf(A1[q][1][o + 3], 0.f);
                    hv0 = fmaxf(A1[q][1][o + 4], 0.f); hv1 = fmaxf(A1[q][1][o + 5], 0.f);
                    hv2 = fmaxf(A1[q][1][o + 6], 0.f); hv3 = fmaxf(A1[q][1][o + 7], 0.f);
                } else {
                    lv0 = fmaxf(A1[q][0][o + 0], 0.f); lv1 = fmaxf(A1[q][0][o + 1], 0.f);
                    lv2 = fmaxf(A1[q][0][o + 2], 0.f); lv3 = fmaxf(A1[q][0][o + 3], 0.f);
                    hv0 = fmaxf(A1[q][0][o + 4], 0.f); hv1 = fmaxf(A1[q][0][o + 5], 0.f);
                    hv2 = fmaxf(A1[q][0][o + 6], 0.f); hv3 = fmaxf(A1[q][0][o + 7], 0.f);
                }
                int p_lv0 = pk2(lv0, lv1), p_lv1 = pk2(lv2, lv3);
                int p_hv0 = pk2(hv0, hv1), p_hv1 = pk2(hv2, hv3);
                int send0 = h ? p_lv0 : p_hv0;
                int send1 = h ? p_lv1 : p_hv1;
                int r0 = __shfl_xor(send0, 32, 64);
                int r1 = __shfl_xor(send1, 32, 64);
                int4v fi;
                fi.x = h ? r0 : p_lv0;
                fi.y = h ? r1 : p_lv1;
                fi.z = h ? p_hv0 : r0;
                fi.w = h ? p_hv1 : r1;
                bf2v[q][kk] = __builtin_bit_cast(short8, fi);
            }
        }

        // ---- layer2 MFMAs (C init = 0; bias via 5th K-group)
        float16 C[2][2];
        #pragma unroll
        for (int q = 0; q < 2; ++q)
            #pragma unroll
            for (int t = 0; t < 2; ++t)
                #pragma unroll
                for (int r = 0; r < 16; ++r) C[q][t][r] = 0.0f;
        #pragma unroll
        for (int kk = 0; kk < 4; ++kk)
            #pragma unroll
            for (int q = 0; q < 2; ++q) {
                C[q][0] = __builtin_amdgcn_mfma_f32_32x32x16_bf16(afrag[0][kk], bf2v[q][kk], C[q][0], 0, 0, 0);
                C[q][1] = __builtin_amdgcn_mfma_f32_32x32x16_bf16(afrag[1][kk], bf2v[q][kk], C[q][1], 0, 0, 0);
            }
        #pragma unroll
        for (int q = 0; q < 2; ++q) {
            C[q][0] = __builtin_amdgcn_mfma_f32_32x32x16_bf16(a2b[0], bone, C[q][0], 0, 0, 0);
            C[q][1] = __builtin_amdgcn_mfma_f32_32x32x16_bf16(a2b[1], bone, C[q][1], 0, 0, 0);
        }

        // ---- layer3 + epilogue per chunk
        #pragma unroll
        for (int q = 0; q < 2; ++q) {
            float partial = 0.0f;
            #pragma unroll
            for (int r = 0; r < 16; ++r) {
                partial += fmaxf(C[q][0][r], 0.0f) * w3r[0][r];
                partial += fmaxf(C[q][1][r], 0.0f) * w3r[1][r];
            }
            float total = partial + __shfl_xor(partial, 32, 64);
            float w = fmaxf(total + b3v, 0.0f);

            if (h == 0 && cvq[q]) {
                int e = ch[q] * 32 + l31;
                edge_w[e] = w;
                if (w > 0.0f) {
                    int col = eidx[N_EDGES + e];
                    atomicAdd(&cnt[col], 1);
                    atomicAdd(&degf[col], w);
                }
            }
        }
    }
}

// ---------------------------------------------------------------------------
// Scan: cnt[100000] -> exclusive offsets off[100001]; cur = off copy.
// s3 also computes dinv = rsqrt(1 + degf) (degf accumulated in k1).
// ---------------------------------------------------------------------------
__global__ __launch_bounds__(1024) void s1_blocksum(const int* __restrict__ cnt,
                                                    int* __restrict__ bsum) {
    __shared__ int sd[1024];
    int t = threadIdx.x;
    int i = blockIdx.x * 1024 + t;
    sd[t] = (i < N_NODES) ? cnt[i] : 0;
    __syncthreads();
    #pragma unroll
    for (int d = 512; d > 0; d >>= 1) {
        if (t < d) sd[t] += sd[t + d];
        __syncthreads();
    }
    if (t == 0) bsum[blockIdx.x] = sd[0];
}

__global__ __launch_bounds__(128) void s2_scanbase(const int* __restrict__ bsum,
                                                   int* __restrict__ bbase,
                                                   int* __restrict__ off) {
    __shared__ int sd[128];
    int t = threadIdx.x;
    int v = (t < NB_SCAN) ? bsum[t] : 0;
    sd[t] = v;
    __syncthreads();
    #pragma unroll
    for (int d = 1; d < 128; d <<= 1) {
        int u = (t >= d) ? sd[t - d] : 0;
        __syncthreads();
        sd[t] += u;
        __syncthreads();
    }
    if (t < NB_SCAN) bbase[t] = sd[t] - v;
    if (t == 127) off[N_NODES] = sd[127];
}

__global__ __launch_bounds__(1024) void s3_blockscan(const int* __restrict__ cnt,
                                                     const int* __restrict__ bbase,
                                                     int* __restrict__ off,
                                                     int* __restrict__ cur,
                                                     const float* __restrict__ degf,
                                                     float* __restrict__ dinv) {
    __shared__ int sd[1024];
    int t = threadIdx.x;
    int i = blockIdx.x * 1024 + t;
    int c = (i < N_NODES) ? cnt[i] : 0;
    sd[t] = c;
    __syncthreads();
    #pragma unroll
    for (int d = 1; d < 1024; d <<= 1) {
        int v = (t >= d) ? sd[t - d] : 0;
        __syncthreads();
        sd[t] += v;
        __syncthreads();
    }
    if (i < N_NODES) {
        int ex = sd[t] - c + bbase[blockIdx.x];
        off[i] = ex;
        cur[i] = ex;
        dinv[i] = rsqrtf(1.0f + degf[i]);
    }
}

// ---------------------------------------------------------------------------
// K_place: scatter live edges into CSR slots (packed {row, w} int2).
// ---------------------------------------------------------------------------
__global__ void k_place(const float* __restrict__ edge_w, const int* __restrict__ eidx,
                        int* __restrict__ cur, int2* __restrict__ recs) {
    int e = blockIdx.x * 256 + threadIdx.x;
    if (e >= N_EDGES) return;
    float w = edge_w[e];
    if (w <= 0.0f) return;
    int col = eidx[N_EDGES + e];
    int pos = atomicAdd(&cur[col], 1);
    recs[pos] = make_int2(eidx[e], __float_as_int(w));
}

// ---------------------------------------------------------------------------
// K3: xws[n] = dinv[n]*(x[n]@Wg) via MFMA; one wave per 32 nodes.
// ---------------------------------------------------------------------------
__global__ __launch_bounds__(256) void k3_xw(
    const float* __restrict__ x, const float* __restrict__ Wg,
    const float* __restrict__ dinv, float* __restrict__ xws)
{
    const int lane = threadIdx.x & 63;
    const int l31 = lane & 31;
    const int h = lane >> 5;
    const int wslot = blockIdx.x * 4 + (threadIdx.x >> 6);

    short8 bw[8][2];
    #pragma unroll
    for (int kk = 0; kk < 8; ++kk)
        #pragma unroll
        for (int u = 0; u < 2; ++u)
            #pragma unroll
            for (int j = 0; j < 8; ++j)
                bw[kk][u][j] = f2bf(Wg[(kk * 16 + 8 * h + j) * NHID + u * 32 + l31]);

    const int NC = N_NODES / 32;
    for (int chunk = wslot; chunk < NC; chunk += gridDim.x * 4) {
        int base = chunk * 32;
        const float* xrow = x + (size_t)(base + l31) * N_FEAT + 8 * h;

        float16 acc0, acc1;
        #pragma unroll
        for (int r = 0; r < 16; ++r) { acc0[r] = 0.0f; acc1[r] = 0.0f; }

        #pragma unroll
        for (int kk = 0; kk < 8; ++kk) {
            float4 p = *(const float4*)(xrow + kk * 16);
            float4 q = *(const float4*)(xrow + kk * 16 + 4);
            short8 af;
            af[0] = f2bf(p.x); af[1] = f2bf(p.y); af[2] = f2bf(p.z); af[3] = f2bf(p.w);
            af[4] = f2bf(q.x); af[5] = f2bf(q.y); af[6] = f2bf(q.z); af[7] = f2bf(q.w);
            acc0 = __builtin_amdgcn_mfma_f32_32x32x16_bf16(af, bw[kk][0], acc0, 0, 0, 0);
            acc1 = __builtin_amdgcn_mfma_f32_32x32x16_bf16(af, bw[kk][1], acc1, 0, 0, 0);
        }

        #pragma unroll
        for (int r = 0; r < 16; ++r) {
            int node = base + (r & 3) + 8 * (r >> 2) + 4 * h;
            float dv = dinv[node];
            xws[node * NHID + l31] = acc0[r] * dv;
            xws[node * NHID + 32 + l31] = acc1[r] * dv;
        }
    }
}

// ---------------------------------------------------------------------------
// K4: fused gather + relu + pool. One wave per 4 nodes; gathers batched
// 4-wide (recs loads are wave-uniform -> s_load; 4 gathers in flight).
// ---------------------------------------------------------------------------
__global__ __launch_bounds__(256) void k4_gather_pool(
    const int* __restrict__ off, const int2* __restrict__ recs,
    const float* __restrict__ xws, const float* __restrict__ dinv,
    const float* __restrict__ bg, const int* __restrict__ batch,
    float* __restrict__ pooled)
{
    const int lane = threadIdx.x & 63;
    const int wv = blockIdx.x * 4 + (threadIdx.x >> 6);
    int n0 = wv * 4;
    if (n0 >= N_NODES) return;
    int n1 = min(n0 + 4, N_NODES);
    float bgl = bg[lane];
    float pacc = 0.0f;
    int curg = batch[n0];
    for (int n = n0; n < n1; ++n) {
        int g = batch[n];
        if (g != curg) {
            atomicAdd(&pooled[curg * NHID + lane], pacc);
            pacc = 0.0f;
            curg = g;
        }
        int o0 = off[n], o1 = off[n + 1];
        float acc = xws[(size_t)n * NHID + lane];
        int j = o0;
        for (; j + 4 <= o1; j += 4) {
            int2 r0 = recs[j], r1 = recs[j + 1], r2 = recs[j + 2], r3 = recs[j + 3];
            float g0 = xws[(size_t)r0.x * NHID + lane];
            float g1 = xws[(size_t)r1.x * NHID + lane];
            float g2 = xws[(size_t)r2.x * NHID + lane];
            float g3 = xws[(size_t)r3.x * NHID + lane];
            acc = fmaf(__int_as_float(r0.y), g0, acc);
            acc = fmaf(__int_as_float(r1.y), g1, acc);
            acc = fmaf(__int_as_float(r2.y), g2, acc);
            acc = fmaf(__int_as_float(r3.y), g3, acc);
        }
        for (; j < o1; ++j) {
            int2 r = recs[j];
            acc = fmaf(__int_as_float(r.y), xws[(size_t)r.x * NHID + lane], acc);
        }
        pacc += fmaxf(dinv[n] * acc + bgl, 0.0f);
    }
    atomicAdd(&pooled[curg * NHID + lane], pacc);
}

// ---------------------------------------------------------------------------
// K6: z = relu(pooled @ W_b1 + b_b1); out = z @ W_b2 + b_b2.
// ---------------------------------------------------------------------------
__global__ __launch_bounds__(64) void k6_final(
    const float* __restrict__ pooled, const float* __restrict__ Wb1,
    const float* __restrict__ bb1, const float* __restrict__ Wb2,
    const float* __restrict__ bb2, float* __restrict__ out) {
    __shared__ float p[NHID];
    int lane = threadIdx.x;
    int g = blockIdx.x;
    p[lane] = pooled[g * NHID + lane];
    __syncthreads();
    float z = bb1[lane];
    #pragma unroll
    for (int k = 0; k < NHID; ++k) z += p[k] * Wb1[k * NHID + lane];
    z = fmaxf(z, 0.0f) * Wb2[lane];
    #pragma unroll
    for (int off = 32; off > 0; off >>= 1)
        z += __shfl_down(z, off, 64);
    if (lane == 0) out[g] = z + bb2[0];
}

// ---------------------------------------------------------------------------
extern "C" void kernel_launch(void* const* d_in, const int* in_sizes, int n_in,
                              void* d_out, int out_size, void* d_ws, size_t ws_size,
                              hipStream_t stream) {
    const float* x        = (const float*)d_in[0];
    const float* ea       = (const float*)d_in[1];
    const float* W_e1     = (const float*)d_in[2];
    const float* b_e1     = (const float*)d_in[3];
    const float* W_e2     = (const float*)d_in[4];
    const float* b_e2     = (const float*)d_in[5];
    const float* W_e3     = (const float*)d_in[6];
    const float* b_e3     = (const float*)d_in[7];
    const float* W_g      = (const float*)d_in[8];
    const float* b_g      = (const float*)d_in[9];
    const float* W_b1     = (const float*)d_in[10];
    const float* b_b1     = (const float*)d_in[11];
    const float* W_b2     = (const float*)d_in[12];
    const float* b_b2     = (const float*)d_in[13];
    const int*   eidx     = (const int*)d_in[14];
    const int*   batch    = (const int*)d_in[15];
    float* out = (float*)d_out;

    // workspace layout (4-byte words). cnt|degf|pooled contiguous -> 1 memset.
    char* wsb = (char*)d_ws;
    int*   cnt    = (int*)wsb;                          // @0       : 100,000
    float* degf   = (float*)(wsb + 4 * 100000);         // @100000  : 100,000
    float* pooled = (float*)(wsb + 4 * 200000);         // @200000  : 16,384
    float* edge_w = (float*)(wsb + 4 * 216448);         // 1,250,000
    int*   off    = (int*)(wsb + 4 * 1466448);          // 100,001
    int*   cur    = (int*)(wsb + 4 * 1566456);          // 100,000
    int*   bsum   = (int*)(wsb + 4 * 1666456);          // 98
    int*   bbase  = (int*)(wsb + 4 * 1666560);          // 98
    int2*  recs   = (int2*)(wsb + 4 * 1666688);         // 1,250,000 int2
    float* dinv   = (float*)(wsb + 4 * 4166688);        // 100,000
    float* xws    = (float*)(wsb + 4 * 4266688);        // 6,400,000

    hipMemsetAsync(wsb, 0, 4 * 216384, stream);   // cnt + degf + pooled

    k1_edge_mlp<<<dim3(1024), dim3(256), 0, stream>>>(
        ea, W_e1, b_e1, W_e2, b_e2, W_e3, b_e3, eidx, edge_w, cnt, degf);
    s1_blocksum<<<dim3(NB_SCAN), dim3(1024), 0, stream>>>(cnt, bsum);
    s2_scanbase<<<dim3(1), dim3(128), 0, stream>>>(bsum, bbase, off);
    s3_blockscan<<<dim3(NB_SCAN), dim3(1024), 0, stream>>>(cnt, bbase, off, cur, degf, dinv);
    k_place<<<dim3((N_EDGES + 255) / 256), dim3(256), 0, stream>>>(edge_w, eidx, cur, recs);
    k3_xw<<<dim3(512), dim3(256), 0, stream>>>(x, W_g, dinv, xws);
    k4_gather_pool<<<dim3(6250), dim3(256), 0, stream>>>(off, recs, xws, dinv, b_g, batch, pooled);
    k6_final<<<dim3(NUM_GRAPHS), dim3(64), 0, stream>>>(pooled, W_b1, b_b1, W_b2, b_b2, out);
}